// Round 6
// baseline (1926.469 us; speedup 1.0000x reference)
//
#include <hip/hip_runtime.h>

#define N_NODES 100000
#define N_EDGES 800000
#define N_LABEL 400000
// IN_CH = 256, OUT_CH = 256, H1 = 128, H2 = 32
// Key algebra: b_gcn cancels in h[dst]-h[src]; h@W1 = S_hat (x @ (W_gcn@W1)).
// So we only ever need p = S_hat(x@Wf) [100k,128], Wf = W_gcn@W1.

// ---------------- init counters ----------------
__global__ void k_zero2(int* __restrict__ a, int* __restrict__ b) {
    int i = blockIdx.x * 256 + threadIdx.x;
    if (i < N_NODES) { a[i] = 0; b[i] = 0; }
}

__global__ void k_count(const int* __restrict__ ei, int* __restrict__ cnt) {
    int e = blockIdx.x * 256 + threadIdx.x;
    if (e < N_EDGES) atomicAdd(&cnt[ei[N_EDGES + e]], 1);  // dst = ei[1][e]
}

__global__ void k_dis(const int* __restrict__ cnt, float* __restrict__ dis) {
    int i = blockIdx.x * 256 + threadIdx.x;
    if (i < N_NODES) dis[i] = rsqrtf((float)(cnt[i] + 1));  // +1 self loop
}

// ---------------- hierarchical exclusive scan: cnt -> rowptr ----------------
__global__ __launch_bounds__(1024) void k_bsum(const int* __restrict__ cnt,
                                               int* __restrict__ bsum) {
    __shared__ int red[1024];
    int t = threadIdx.x;
    int i = blockIdx.x * 1024 + t;
    red[t] = (i < N_NODES) ? cnt[i] : 0;
    __syncthreads();
    #pragma unroll
    for (int off = 512; off; off >>= 1) {
        if (t < off) red[t] += red[t + off];
        __syncthreads();
    }
    if (t == 0) bsum[blockIdx.x] = red[0];
}

__global__ void k_bscan(int* __restrict__ bsum, int nb) {
    __shared__ int s[128];
    int t = threadIdx.x;
    s[t] = (t < nb) ? bsum[t] : 0;
    __syncthreads();
    #pragma unroll
    for (int off = 1; off < 128; off <<= 1) {
        int v = (t >= off) ? s[t - off] : 0;
        __syncthreads();
        s[t] += v;
        __syncthreads();
    }
    if (t < nb) bsum[t] = t ? s[t - 1] : 0;
}

__global__ __launch_bounds__(1024) void k_rowptr(const int* __restrict__ cnt,
                                                 const int* __restrict__ bsum,
                                                 int* __restrict__ rowptr) {
    __shared__ int s[1024];
    int t = threadIdx.x;
    int i = blockIdx.x * 1024 + t;
    int v = (i < N_NODES) ? cnt[i] : 0;
    s[t] = v;
    __syncthreads();
    #pragma unroll
    for (int off = 1; off < 1024; off <<= 1) {
        int u = (t >= off) ? s[t - off] : 0;
        __syncthreads();
        s[t] += u;
        __syncthreads();
    }
    int excl = s[t] - v + bsum[blockIdx.x];
    if (i < N_NODES) rowptr[i] = excl;
    if (i == N_NODES - 1) rowptr[N_NODES] = excl + v;  // == N_EDGES
}

__global__ void k_fill(const int* __restrict__ ei, const int* __restrict__ rowptr,
                       int* __restrict__ cursor, int* __restrict__ csr) {
    int e = blockIdx.x * 256 + threadIdx.x;
    if (e >= N_EDGES) return;
    int src = ei[e];
    int dst = ei[N_EDGES + e];
    int pos = rowptr[dst] + atomicAdd(&cursor[dst], 1);
    csr[pos] = src;
}

// ---------------- fp32 tiled GEMM v3: double-buffered LDS, 1 sync/K-step ----
__global__ __launch_bounds__(256) void gemm_f32(
    const float* __restrict__ A, const float* __restrict__ B,
    float* __restrict__ C, int M, int N, int K,
    const float* __restrict__ rowscale) {
    __shared__ float As[2][16][132];
    __shared__ float Bs[2][16][132];

    const int tid = threadIdx.x;
    const int tx = tid & 15, ty = tid >> 4;
    const int m0 = blockIdx.x * 128, n0 = blockIdx.y * 128;

    const int ar = tid >> 2;        // A row in tile (+64 second half)
    const int ac = (tid & 3) * 4;   // A col in tile
    const int bk = tid >> 5;        // B k-row (+8 second half)
    const int bc = (tid & 31) * 4;  // B col in tile

    float acc[8][8] = {};
    float4 va[2], vb[2];

    auto loadG = [&](int k0) {
        #pragma unroll
        for (int hh = 0; hh < 2; ++hh) {
            int row = m0 + ar + hh * 64;
            va[hh] = make_float4(0.f, 0.f, 0.f, 0.f);
            if (row < M) va[hh] = *(const float4*)&A[(size_t)row * K + k0 + ac];
            vb[hh] = *(const float4*)&B[(size_t)(k0 + bk + hh * 8) * N + n0 + bc];
        }
    };
    auto storeL = [&](int buf) {
        #pragma unroll
        for (int hh = 0; hh < 2; ++hh) {
            As[buf][ac + 0][ar + hh * 64] = va[hh].x;
            As[buf][ac + 1][ar + hh * 64] = va[hh].y;
            As[buf][ac + 2][ar + hh * 64] = va[hh].z;
            As[buf][ac + 3][ar + hh * 64] = va[hh].w;
            *(float4*)&Bs[buf][bk + hh * 8][bc] = vb[hh];
        }
    };

    loadG(0);
    storeL(0);
    __syncthreads();

    int cur = 0;
    for (int k0 = 16;; k0 += 16) {
        const bool last = (k0 >= K);
        if (!last) loadG(k0);  // issue next tile's global loads early

        #pragma unroll
        for (int kk = 0; kk < 16; ++kk) {
            const float4 a0 = *(const float4*)&As[cur][kk][ty * 8];
            const float4 a1 = *(const float4*)&As[cur][kk][ty * 8 + 4];
            const float4 b0 = *(const float4*)&Bs[cur][kk][tx * 8];
            const float4 b1 = *(const float4*)&Bs[cur][kk][tx * 8 + 4];
            const float aa[8] = {a0.x, a0.y, a0.z, a0.w, a1.x, a1.y, a1.z, a1.w};
            const float bb[8] = {b0.x, b0.y, b0.z, b0.w, b1.x, b1.y, b1.z, b1.w};
            #pragma unroll
            for (int i = 0; i < 8; ++i)
                #pragma unroll
                for (int j = 0; j < 8; ++j)
                    acc[i][j] = fmaf(aa[i], bb[j], acc[i][j]);
        }
        if (last) break;
        storeL(cur ^ 1);
        __syncthreads();
        cur ^= 1;
    }

    #pragma unroll
    for (int i = 0; i < 8; ++i) {
        int row = m0 + ty * 8 + i;
        if (row < M) {
            float s = rowscale ? rowscale[row] : 1.0f;
            float4 c0 = {acc[i][0] * s, acc[i][1] * s, acc[i][2] * s, acc[i][3] * s};
            float4 c1 = {acc[i][4] * s, acc[i][5] * s, acc[i][6] * s, acc[i][7] * s};
            *(float4*)&C[(size_t)row * N + n0 + tx * 8] = c0;
            *(float4*)&C[(size_t)row * N + n0 + tx * 8 + 4] = c1;
        }
    }
}

// ---------------- CSR gather v2: 4 independent row loads in flight ----------
__global__ __launch_bounds__(256) void k_gather(
    const float* __restrict__ qs, const int* __restrict__ rowptr,
    const int* __restrict__ csr, const float* __restrict__ dis,
    float* __restrict__ p) {
    int node = blockIdx.x * 4 + (threadIdx.x >> 6);
    if (node >= N_NODES) return;
    int lane = threadIdx.x & 63;
    int beg = rowptr[node], end = rowptr[node + 1];
    float2 acc = *(const float2*)&qs[(size_t)node * 128 + lane * 2];
    int j = beg;
    for (; j + 4 <= end; j += 4) {
        int s0 = csr[j], s1 = csr[j + 1], s2 = csr[j + 2], s3 = csr[j + 3];
        float2 v0 = *(const float2*)&qs[(size_t)s0 * 128 + lane * 2];
        float2 v1 = *(const float2*)&qs[(size_t)s1 * 128 + lane * 2];
        float2 v2 = *(const float2*)&qs[(size_t)s2 * 128 + lane * 2];
        float2 v3 = *(const float2*)&qs[(size_t)s3 * 128 + lane * 2];
        acc.x += v0.x; acc.y += v0.y;
        acc.x += v1.x; acc.y += v1.y;
        acc.x += v2.x; acc.y += v2.y;
        acc.x += v3.x; acc.y += v3.y;
    }
    for (; j < end; ++j) {
        int src = csr[j];
        float2 v = *(const float2*)&qs[(size_t)src * 128 + lane * 2];
        acc.x += v.x;
        acc.y += v.y;
    }
    float d = dis[node];
    float2 r = {acc.x * d, acc.y * d};
    *(float2*)&p[(size_t)node * 128 + lane * 2] = r;
}

// ---------------- fused edge MLP v3: groups of 4, prefetch next group -------
// 16 edges/wave in 4 groups; rows for group g+1 loaded while layer2 runs on g.
__global__ __launch_bounds__(256, 4) void k_edge_mlp(
    const float* __restrict__ p, const int* __restrict__ eli,
    const float* __restrict__ b1, const float* __restrict__ W2,
    const float* __restrict__ b2, const float* __restrict__ W3,
    const float* __restrict__ b3, float* __restrict__ out) {
    __shared__ float st[4][4][128];  // [wave][slot][128]

    const int tid = threadIdx.x;
    const int wave = tid >> 6, lane = tid & 63;
    const int o = lane & 31, kh = lane >> 5;

    // W2 column-half in registers (reused for all 16 edges)
    float w2r[64];
    #pragma unroll
    for (int i = 0; i < 64; ++i)
        w2r[i] = W2[(kh * 64 + i) * 32 + o];

    const float b2r = b2[o];
    const float w3r = W3[o];
    const float b3r = b3[0];
    const float2 bb = *(const float2*)&b1[lane * 2];

    const int e0 = (blockIdx.x * 4 + wave) * 16;

    float2 pd[4], ps[4];
    #pragma unroll
    for (int t = 0; t < 4; ++t) {
        int s = eli[e0 + t], d = eli[N_LABEL + e0 + t];
        pd[t] = *(const float2*)&p[(size_t)d * 128 + lane * 2];
        ps[t] = *(const float2*)&p[(size_t)s * 128 + lane * 2];
    }

    #pragma unroll
    for (int g = 0; g < 4; ++g) {
        // layer1 for current group -> LDS slots
        #pragma unroll
        for (int t = 0; t < 4; ++t) {
            float t0 = fmaxf(pd[t].x - ps[t].x + bb.x, 0.f);
            float t1 = fmaxf(pd[t].y - ps[t].y + bb.y, 0.f);
            *(float2*)&st[wave][t][lane * 2] = make_float2(t0, t1);
        }
        // prefetch next group's rows (hides under layer2 below)
        if (g < 3) {
            #pragma unroll
            for (int t = 0; t < 4; ++t) {
                int e = e0 + (g + 1) * 4 + t;
                int s = eli[e], d = eli[N_LABEL + e];
                pd[t] = *(const float2*)&p[(size_t)d * 128 + lane * 2];
                ps[t] = *(const float2*)&p[(size_t)s * 128 + lane * 2];
            }
        }
        // layer2: 4 independent accumulators, broadcast ds_read_b128
        float acc[4] = {0.f, 0.f, 0.f, 0.f};
        #pragma unroll
        for (int i = 0; i < 64; i += 4) {
            #pragma unroll
            for (int t = 0; t < 4; ++t) {
                const float4 tv = *(const float4*)&st[wave][t][kh * 64 + i];
                acc[t] = fmaf(tv.x, w2r[i + 0], acc[t]);
                acc[t] = fmaf(tv.y, w2r[i + 1], acc[t]);
                acc[t] = fmaf(tv.z, w2r[i + 2], acc[t]);
                acc[t] = fmaf(tv.w, w2r[i + 3], acc[t]);
            }
        }
        #pragma unroll
        for (int t = 0; t < 4; ++t) {
            float a = acc[t] + __shfl_xor(acc[t], 32);   // merge k-halves
            float u = fmaxf(a + b2r, 0.f) * w3r;          // layer3 partial
            #pragma unroll
            for (int m = 16; m; m >>= 1) u += __shfl_xor(u, m);
            if (lane == 0) out[e0 + g * 4 + t] = u + b3r;
        }
    }
}

// ---------------- launch ----------------
extern "C" void kernel_launch(void* const* d_in, const int* in_sizes, int n_in,
                              void* d_out, int out_size, void* d_ws, size_t ws_size,
                              hipStream_t stream) {
    const float* x   = (const float*)d_in[0];
    const int*   ei  = (const int*)d_in[1];
    const int*   eli = (const int*)d_in[2];
    const float* Wg  = (const float*)d_in[3];
    // d_in[4] = b_gcn : cancels in h[dst]-h[src], unused
    const float* W1  = (const float*)d_in[5];
    const float* b1  = (const float*)d_in[6];
    const float* W2  = (const float*)d_in[7];
    const float* b2  = (const float*)d_in[8];
    const float* W3  = (const float*)d_in[9];
    const float* b3  = (const float*)d_in[10];
    float* out = (float*)d_out;

    // ---- workspace layout (bytes), all regions disjoint & 16B-aligned ----
    char* ws = (char*)d_ws;
    float* dis    = (float*)(ws + 0);           // 400 KB
    int*   cnt    = (int*)(ws + 524288);        // 400 KB
    int*   cursor = (int*)(ws + 1048576);       // 400 KB
    int*   rowptr = (int*)(ws + 1572864);       // 400 KB + 4
    int*   bsum   = (int*)(ws + 2000000);       // 512 B (98 ints)
    int*   csr    = (int*)(ws + 2097152);       // 3.2 MB (4 MB reserved)
    float* Wf     = (float*)(ws + 6291456);     // 128 KB
    float* qs     = (float*)(ws + 8388608);     // 51.2 MB
    float* p      = (float*)(ws + 59588608);    // 51.2 MB

    const int NB = (N_NODES + 1023) / 1024;     // 98

    // CSR build + degree norm
    k_zero2<<<(N_NODES + 255) / 256, 256, 0, stream>>>(cnt, cursor);
    k_count<<<(N_EDGES + 255) / 256, 256, 0, stream>>>(ei, cnt);
    k_dis<<<(N_NODES + 255) / 256, 256, 0, stream>>>(cnt, dis);
    k_bsum<<<NB, 1024, 0, stream>>>(cnt, bsum);
    k_bscan<<<1, 128, 0, stream>>>(bsum, NB);
    k_rowptr<<<NB, 1024, 0, stream>>>(cnt, bsum, rowptr);
    k_fill<<<(N_EDGES + 255) / 256, 256, 0, stream>>>(ei, rowptr, cursor, csr);

    // Wf = W_gcn @ W1   [256,256]@[256,128]
    gemm_f32<<<dim3(2, 1), 256, 0, stream>>>(Wg, W1, Wf, 256, 128, 256, nullptr);

    // qs = (x @ Wf) * dis[row]   [100000,256]@[256,128]
    gemm_f32<<<dim3((N_NODES + 127) / 128, 1), 256, 0, stream>>>(
        x, Wf, qs, N_NODES, 128, 256, dis);

    // p[i] = dis[i] * (qs[i] + sum_{src->i} qs[src])
    k_gather<<<(N_NODES + 3) / 4, 256, 0, stream>>>(qs, rowptr, csr, dis, p);

    // fused per-edge MLP: 16 edges/wave, 4 waves/block
    k_edge_mlp<<<N_LABEL / 64, 256, 0, stream>>>(p, eli, b1, W2, b2, W3, b3, out);
}

// Round 7
// 456.108 us; speedup vs baseline: 4.2237x; 4.2237x over previous
//
#include <hip/hip_runtime.h>

#define N_NODES 100000
#define N_EDGES 800000
#define N_LABEL 400000
// IN_CH = 256, OUT_CH = 256, H1 = 128, H2 = 32
// Key algebra: b_gcn cancels in h[dst]-h[src]; h@W1 = S_hat (x @ (W_gcn@W1)).
// So we only ever need p = S_hat(x@Wf) [100k,128], Wf = W_gcn@W1.

// ---------------- init counters ----------------
__global__ void k_zero2(int* __restrict__ a, int* __restrict__ b) {
    int i = blockIdx.x * 256 + threadIdx.x;
    if (i < N_NODES) { a[i] = 0; b[i] = 0; }
}

__global__ void k_count(const int* __restrict__ ei, int* __restrict__ cnt) {
    int e = blockIdx.x * 256 + threadIdx.x;
    if (e < N_EDGES) atomicAdd(&cnt[ei[N_EDGES + e]], 1);  // dst = ei[1][e]
}

__global__ void k_dis(const int* __restrict__ cnt, float* __restrict__ dis) {
    int i = blockIdx.x * 256 + threadIdx.x;
    if (i < N_NODES) dis[i] = rsqrtf((float)(cnt[i] + 1));  // +1 self loop
}

// ---------------- hierarchical exclusive scan: cnt -> rowptr ----------------
__global__ __launch_bounds__(1024) void k_bsum(const int* __restrict__ cnt,
                                               int* __restrict__ bsum) {
    __shared__ int red[1024];
    int t = threadIdx.x;
    int i = blockIdx.x * 1024 + t;
    red[t] = (i < N_NODES) ? cnt[i] : 0;
    __syncthreads();
    #pragma unroll
    for (int off = 512; off; off >>= 1) {
        if (t < off) red[t] += red[t + off];
        __syncthreads();
    }
    if (t == 0) bsum[blockIdx.x] = red[0];
}

__global__ void k_bscan(int* __restrict__ bsum, int nb) {
    __shared__ int s[128];
    int t = threadIdx.x;
    s[t] = (t < nb) ? bsum[t] : 0;
    __syncthreads();
    #pragma unroll
    for (int off = 1; off < 128; off <<= 1) {
        int v = (t >= off) ? s[t - off] : 0;
        __syncthreads();
        s[t] += v;
        __syncthreads();
    }
    if (t < nb) bsum[t] = t ? s[t - 1] : 0;
}

__global__ __launch_bounds__(1024) void k_rowptr(const int* __restrict__ cnt,
                                                 const int* __restrict__ bsum,
                                                 int* __restrict__ rowptr) {
    __shared__ int s[1024];
    int t = threadIdx.x;
    int i = blockIdx.x * 1024 + t;
    int v = (i < N_NODES) ? cnt[i] : 0;
    s[t] = v;
    __syncthreads();
    #pragma unroll
    for (int off = 1; off < 1024; off <<= 1) {
        int u = (t >= off) ? s[t - off] : 0;
        __syncthreads();
        s[t] += u;
        __syncthreads();
    }
    int excl = s[t] - v + bsum[blockIdx.x];
    if (i < N_NODES) rowptr[i] = excl;
    if (i == N_NODES - 1) rowptr[N_NODES] = excl + v;  // == N_EDGES
}

__global__ void k_fill(const int* __restrict__ ei, const int* __restrict__ rowptr,
                       int* __restrict__ cursor, int* __restrict__ csr) {
    int e = blockIdx.x * 256 + threadIdx.x;
    if (e >= N_EDGES) return;
    int src = ei[e];
    int dst = ei[N_EDGES + e];
    int pos = rowptr[dst] + atomicAdd(&cursor[dst], 1);
    csr[pos] = src;
}

// ---------------- fp32 tiled GEMM v3: double-buffered LDS, 1 sync/K-step ----
__global__ __launch_bounds__(256) void gemm_f32(
    const float* __restrict__ A, const float* __restrict__ B,
    float* __restrict__ C, int M, int N, int K,
    const float* __restrict__ rowscale) {
    __shared__ float As[2][16][132];
    __shared__ float Bs[2][16][132];

    const int tid = threadIdx.x;
    const int tx = tid & 15, ty = tid >> 4;
    const int m0 = blockIdx.x * 128, n0 = blockIdx.y * 128;

    const int ar = tid >> 2;        // A row in tile (+64 second half)
    const int ac = (tid & 3) * 4;   // A col in tile
    const int bk = tid >> 5;        // B k-row (+8 second half)
    const int bc = (tid & 31) * 4;  // B col in tile

    float acc[8][8] = {};
    float4 va[2], vb[2];

    auto loadG = [&](int k0) {
        #pragma unroll
        for (int hh = 0; hh < 2; ++hh) {
            int row = m0 + ar + hh * 64;
            va[hh] = make_float4(0.f, 0.f, 0.f, 0.f);
            if (row < M) va[hh] = *(const float4*)&A[(size_t)row * K + k0 + ac];
            vb[hh] = *(const float4*)&B[(size_t)(k0 + bk + hh * 8) * N + n0 + bc];
        }
    };
    auto storeL = [&](int buf) {
        #pragma unroll
        for (int hh = 0; hh < 2; ++hh) {
            As[buf][ac + 0][ar + hh * 64] = va[hh].x;
            As[buf][ac + 1][ar + hh * 64] = va[hh].y;
            As[buf][ac + 2][ar + hh * 64] = va[hh].z;
            As[buf][ac + 3][ar + hh * 64] = va[hh].w;
            *(float4*)&Bs[buf][bk + hh * 8][bc] = vb[hh];
        }
    };

    loadG(0);
    storeL(0);
    __syncthreads();

    int cur = 0;
    for (int k0 = 16;; k0 += 16) {
        const bool last = (k0 >= K);
        if (!last) loadG(k0);  // issue next tile's global loads early

        #pragma unroll
        for (int kk = 0; kk < 16; ++kk) {
            const float4 a0 = *(const float4*)&As[cur][kk][ty * 8];
            const float4 a1 = *(const float4*)&As[cur][kk][ty * 8 + 4];
            const float4 b0 = *(const float4*)&Bs[cur][kk][tx * 8];
            const float4 b1 = *(const float4*)&Bs[cur][kk][tx * 8 + 4];
            const float aa[8] = {a0.x, a0.y, a0.z, a0.w, a1.x, a1.y, a1.z, a1.w};
            const float bb[8] = {b0.x, b0.y, b0.z, b0.w, b1.x, b1.y, b1.z, b1.w};
            #pragma unroll
            for (int i = 0; i < 8; ++i)
                #pragma unroll
                for (int j = 0; j < 8; ++j)
                    acc[i][j] = fmaf(aa[i], bb[j], acc[i][j]);
        }
        if (last) break;
        storeL(cur ^ 1);
        __syncthreads();
        cur ^= 1;
    }

    #pragma unroll
    for (int i = 0; i < 8; ++i) {
        int row = m0 + ty * 8 + i;
        if (row < M) {
            float s = rowscale ? rowscale[row] : 1.0f;
            float4 c0 = {acc[i][0] * s, acc[i][1] * s, acc[i][2] * s, acc[i][3] * s};
            float4 c1 = {acc[i][4] * s, acc[i][5] * s, acc[i][6] * s, acc[i][7] * s};
            *(float4*)&C[(size_t)row * N + n0 + tx * 8] = c0;
            *(float4*)&C[(size_t)row * N + n0 + tx * 8 + 4] = c1;
        }
    }
}

// ---------------- CSR gather v2: 4 independent row loads in flight ----------
__global__ __launch_bounds__(256) void k_gather(
    const float* __restrict__ qs, const int* __restrict__ rowptr,
    const int* __restrict__ csr, const float* __restrict__ dis,
    float* __restrict__ p) {
    int node = blockIdx.x * 4 + (threadIdx.x >> 6);
    if (node >= N_NODES) return;
    int lane = threadIdx.x & 63;
    int beg = rowptr[node], end = rowptr[node + 1];
    float2 acc = *(const float2*)&qs[(size_t)node * 128 + lane * 2];
    int j = beg;
    for (; j + 4 <= end; j += 4) {
        int s0 = csr[j], s1 = csr[j + 1], s2 = csr[j + 2], s3 = csr[j + 3];
        float2 v0 = *(const float2*)&qs[(size_t)s0 * 128 + lane * 2];
        float2 v1 = *(const float2*)&qs[(size_t)s1 * 128 + lane * 2];
        float2 v2 = *(const float2*)&qs[(size_t)s2 * 128 + lane * 2];
        float2 v3 = *(const float2*)&qs[(size_t)s3 * 128 + lane * 2];
        acc.x += v0.x; acc.y += v0.y;
        acc.x += v1.x; acc.y += v1.y;
        acc.x += v2.x; acc.y += v2.y;
        acc.x += v3.x; acc.y += v3.y;
    }
    for (; j < end; ++j) {
        int src = csr[j];
        float2 v = *(const float2*)&qs[(size_t)src * 128 + lane * 2];
        acc.x += v.x;
        acc.y += v.y;
    }
    float d = dis[node];
    float2 r = {acc.x * d, acc.y * d};
    *(float2*)&p[(size_t)node * 128 + lane * 2] = r;
}

// ---------------- fused edge MLP (v2, proven: W2 in regs, no spill) ---------
// thread (o = lane&31, kh = lane>>5) holds W2[kh*64 + i][o], i<64.
// Per edge: layer1 in regs -> t row in per-wave LDS -> broadcast ds_read_b128
// + 64 FMA -> shfl_xor(32) k-half merge -> relu,*W3 -> 5-shfl reduce -> store.
// 16 edges per wave, 4 waves per block, grid = 400000/64 = 6250 blocks.
// NOTE: v3 (group-of-4 + prefetch regs) spilled to scratch (3.3GB fetch,
// 2.6GB write, 10x slower). Do NOT add per-thread arrays here.
__global__ __launch_bounds__(256, 4) void k_edge_mlp(
    const float* __restrict__ p, const int* __restrict__ eli,
    const float* __restrict__ b1, const float* __restrict__ W2,
    const float* __restrict__ b2, const float* __restrict__ W3,
    const float* __restrict__ b3, float* __restrict__ out) {
    __shared__ float st[4][128];

    const int tid = threadIdx.x;
    const int wave = tid >> 6, lane = tid & 63;
    const int o = lane & 31, kh = lane >> 5;

    float w2r[64];
    #pragma unroll
    for (int i = 0; i < 64; ++i)
        w2r[i] = W2[(kh * 64 + i) * 32 + o];

    const float b2r = b2[o];
    const float w3r = W3[o];
    const float b3r = b3[0];
    const float2 bb = *(const float2*)&b1[lane * 2];

    const int e0 = (blockIdx.x * 4 + wave) * 16;

    #pragma unroll 2
    for (int t = 0; t < 16; ++t) {
        const int e = e0 + t;
        const int src = eli[e];
        const int dst = eli[N_LABEL + e];
        const float2 pd = *(const float2*)&p[(size_t)dst * 128 + lane * 2];
        const float2 ps = *(const float2*)&p[(size_t)src * 128 + lane * 2];
        const float t0 = fmaxf(pd.x - ps.x + bb.x, 0.f);
        const float t1 = fmaxf(pd.y - ps.y + bb.y, 0.f);
        *(float2*)&st[wave][lane * 2] = make_float2(t0, t1);
        float acc = 0.f;
        #pragma unroll
        for (int i = 0; i < 64; i += 4) {
            const float4 tv = *(const float4*)&st[wave][kh * 64 + i];
            acc = fmaf(tv.x, w2r[i + 0], acc);
            acc = fmaf(tv.y, w2r[i + 1], acc);
            acc = fmaf(tv.z, w2r[i + 2], acc);
            acc = fmaf(tv.w, w2r[i + 3], acc);
        }
        acc += __shfl_xor(acc, 32);               // merge k-halves
        float u = fmaxf(acc + b2r, 0.f) * w3r;    // layer3 partial per o
        #pragma unroll
        for (int m = 16; m; m >>= 1) u += __shfl_xor(u, m);
        if (lane == 0) out[e] = u + b3r;
    }
}

// ---------------- launch ----------------
extern "C" void kernel_launch(void* const* d_in, const int* in_sizes, int n_in,
                              void* d_out, int out_size, void* d_ws, size_t ws_size,
                              hipStream_t stream) {
    const float* x   = (const float*)d_in[0];
    const int*   ei  = (const int*)d_in[1];
    const int*   eli = (const int*)d_in[2];
    const float* Wg  = (const float*)d_in[3];
    // d_in[4] = b_gcn : cancels in h[dst]-h[src], unused
    const float* W1  = (const float*)d_in[5];
    const float* b1  = (const float*)d_in[6];
    const float* W2  = (const float*)d_in[7];
    const float* b2  = (const float*)d_in[8];
    const float* W3  = (const float*)d_in[9];
    const float* b3  = (const float*)d_in[10];
    float* out = (float*)d_out;

    // ---- workspace layout (bytes), all regions disjoint & 16B-aligned ----
    char* ws = (char*)d_ws;
    float* dis    = (float*)(ws + 0);           // 400 KB
    int*   cnt    = (int*)(ws + 524288);        // 400 KB
    int*   cursor = (int*)(ws + 1048576);       // 400 KB
    int*   rowptr = (int*)(ws + 1572864);       // 400 KB + 4
    int*   bsum   = (int*)(ws + 2000000);       // 512 B (98 ints)
    int*   csr    = (int*)(ws + 2097152);       // 3.2 MB (4 MB reserved)
    float* Wf     = (float*)(ws + 6291456);     // 128 KB
    float* qs     = (float*)(ws + 8388608);     // 51.2 MB
    float* p      = (float*)(ws + 59588608);    // 51.2 MB

    const int NB = (N_NODES + 1023) / 1024;     // 98

    // CSR build + degree norm
    k_zero2<<<(N_NODES + 255) / 256, 256, 0, stream>>>(cnt, cursor);
    k_count<<<(N_EDGES + 255) / 256, 256, 0, stream>>>(ei, cnt);
    k_dis<<<(N_NODES + 255) / 256, 256, 0, stream>>>(cnt, dis);
    k_bsum<<<NB, 1024, 0, stream>>>(cnt, bsum);
    k_bscan<<<1, 128, 0, stream>>>(bsum, NB);
    k_rowptr<<<NB, 1024, 0, stream>>>(cnt, bsum, rowptr);
    k_fill<<<(N_EDGES + 255) / 256, 256, 0, stream>>>(ei, rowptr, cursor, csr);

    // Wf = W_gcn @ W1   [256,256]@[256,128]
    gemm_f32<<<dim3(2, 1), 256, 0, stream>>>(Wg, W1, Wf, 256, 128, 256, nullptr);

    // qs = (x @ Wf) * dis[row]   [100000,256]@[256,128]
    gemm_f32<<<dim3((N_NODES + 127) / 128, 1), 256, 0, stream>>>(
        x, Wf, qs, N_NODES, 128, 256, dis);

    // p[i] = dis[i] * (qs[i] + sum_{src->i} qs[src])
    k_gather<<<(N_NODES + 3) / 4, 256, 0, stream>>>(qs, rowptr, csr, dis, p);

    // fused per-edge MLP: 16 edges/wave, 4 waves/block
    k_edge_mlp<<<N_LABEL / 64, 256, 0, stream>>>(p, eli, b1, W2, b2, W3, b3, out);
}

// Round 8
// 432.891 us; speedup vs baseline: 4.4502x; 1.0536x over previous
//
#include <hip/hip_runtime.h>

#define N_NODES 100000
#define N_EDGES 800000
#define N_LABEL 400000
// IN_CH = 256, OUT_CH = 256, H1 = 128, H2 = 32
// Key algebra: b_gcn cancels in h[dst]-h[src]; h@W1 = S_hat (x @ (W_gcn@W1)).
// So we only ever need p = S_hat(x@Wf) [100k,128], Wf = W_gcn@W1.

// ---------------- init counters ----------------
__global__ void k_zero2(int* __restrict__ a, int* __restrict__ b) {
    int i = blockIdx.x * 256 + threadIdx.x;
    if (i < N_NODES) { a[i] = 0; b[i] = 0; }
}

__global__ void k_count(const int* __restrict__ ei, int* __restrict__ cnt) {
    int e = blockIdx.x * 256 + threadIdx.x;
    if (e < N_EDGES) atomicAdd(&cnt[ei[N_EDGES + e]], 1);  // dst = ei[1][e]
}

__global__ void k_dis(const int* __restrict__ cnt, float* __restrict__ dis) {
    int i = blockIdx.x * 256 + threadIdx.x;
    if (i < N_NODES) dis[i] = rsqrtf((float)(cnt[i] + 1));  // +1 self loop
}

// ---------------- hierarchical exclusive scan: cnt -> rowptr ----------------
__global__ __launch_bounds__(1024) void k_bsum(const int* __restrict__ cnt,
                                               int* __restrict__ bsum) {
    __shared__ int red[1024];
    int t = threadIdx.x;
    int i = blockIdx.x * 1024 + t;
    red[t] = (i < N_NODES) ? cnt[i] : 0;
    __syncthreads();
    #pragma unroll
    for (int off = 512; off; off >>= 1) {
        if (t < off) red[t] += red[t + off];
        __syncthreads();
    }
    if (t == 0) bsum[blockIdx.x] = red[0];
}

__global__ void k_bscan(int* __restrict__ bsum, int nb) {
    __shared__ int s[128];
    int t = threadIdx.x;
    s[t] = (t < nb) ? bsum[t] : 0;
    __syncthreads();
    #pragma unroll
    for (int off = 1; off < 128; off <<= 1) {
        int v = (t >= off) ? s[t - off] : 0;
        __syncthreads();
        s[t] += v;
        __syncthreads();
    }
    if (t < nb) bsum[t] = t ? s[t - 1] : 0;
}

__global__ __launch_bounds__(1024) void k_rowptr(const int* __restrict__ cnt,
                                                 const int* __restrict__ bsum,
                                                 int* __restrict__ rowptr) {
    __shared__ int s[1024];
    int t = threadIdx.x;
    int i = blockIdx.x * 1024 + t;
    int v = (i < N_NODES) ? cnt[i] : 0;
    s[t] = v;
    __syncthreads();
    #pragma unroll
    for (int off = 1; off < 1024; off <<= 1) {
        int u = (t >= off) ? s[t - off] : 0;
        __syncthreads();
        s[t] += u;
        __syncthreads();
    }
    int excl = s[t] - v + bsum[blockIdx.x];
    if (i < N_NODES) rowptr[i] = excl;
    if (i == N_NODES - 1) rowptr[N_NODES] = excl + v;  // == N_EDGES
}

__global__ void k_fill(const int* __restrict__ ei, const int* __restrict__ rowptr,
                       int* __restrict__ cursor, int* __restrict__ csr) {
    int e = blockIdx.x * 256 + threadIdx.x;
    if (e >= N_EDGES) return;
    int src = ei[e];
    int dst = ei[N_EDGES + e];
    int pos = rowptr[dst] + atomicAdd(&cursor[dst], 1);
    csr[pos] = src;
}

// ---------------- fp32 tiled GEMM v3: double-buffered LDS, 1 sync/K-step ----
__global__ __launch_bounds__(256) void gemm_f32(
    const float* __restrict__ A, const float* __restrict__ B,
    float* __restrict__ C, int M, int N, int K,
    const float* __restrict__ rowscale) {
    __shared__ float As[2][16][132];
    __shared__ float Bs[2][16][132];

    const int tid = threadIdx.x;
    const int tx = tid & 15, ty = tid >> 4;
    const int m0 = blockIdx.x * 128, n0 = blockIdx.y * 128;

    const int ar = tid >> 2;        // A row in tile (+64 second half)
    const int ac = (tid & 3) * 4;   // A col in tile
    const int bk = tid >> 5;        // B k-row (+8 second half)
    const int bc = (tid & 31) * 4;  // B col in tile

    float acc[8][8] = {};
    float4 va[2], vb[2];

    auto loadG = [&](int k0) {
        #pragma unroll
        for (int hh = 0; hh < 2; ++hh) {
            int row = m0 + ar + hh * 64;
            va[hh] = make_float4(0.f, 0.f, 0.f, 0.f);
            if (row < M) va[hh] = *(const float4*)&A[(size_t)row * K + k0 + ac];
            vb[hh] = *(const float4*)&B[(size_t)(k0 + bk + hh * 8) * N + n0 + bc];
        }
    };
    auto storeL = [&](int buf) {
        #pragma unroll
        for (int hh = 0; hh < 2; ++hh) {
            As[buf][ac + 0][ar + hh * 64] = va[hh].x;
            As[buf][ac + 1][ar + hh * 64] = va[hh].y;
            As[buf][ac + 2][ar + hh * 64] = va[hh].z;
            As[buf][ac + 3][ar + hh * 64] = va[hh].w;
            *(float4*)&Bs[buf][bk + hh * 8][bc] = vb[hh];
        }
    };

    loadG(0);
    storeL(0);
    __syncthreads();

    int cur = 0;
    for (int k0 = 16;; k0 += 16) {
        const bool last = (k0 >= K);
        if (!last) loadG(k0);  // issue next tile's global loads early

        #pragma unroll
        for (int kk = 0; kk < 16; ++kk) {
            const float4 a0 = *(const float4*)&As[cur][kk][ty * 8];
            const float4 a1 = *(const float4*)&As[cur][kk][ty * 8 + 4];
            const float4 b0 = *(const float4*)&Bs[cur][kk][tx * 8];
            const float4 b1 = *(const float4*)&Bs[cur][kk][tx * 8 + 4];
            const float aa[8] = {a0.x, a0.y, a0.z, a0.w, a1.x, a1.y, a1.z, a1.w};
            const float bb[8] = {b0.x, b0.y, b0.z, b0.w, b1.x, b1.y, b1.z, b1.w};
            #pragma unroll
            for (int i = 0; i < 8; ++i)
                #pragma unroll
                for (int j = 0; j < 8; ++j)
                    acc[i][j] = fmaf(aa[i], bb[j], acc[i][j]);
        }
        if (last) break;
        storeL(cur ^ 1);
        __syncthreads();
        cur ^= 1;
    }

    #pragma unroll
    for (int i = 0; i < 8; ++i) {
        int row = m0 + ty * 8 + i;
        if (row < M) {
            float s = rowscale ? rowscale[row] : 1.0f;
            float4 c0 = {acc[i][0] * s, acc[i][1] * s, acc[i][2] * s, acc[i][3] * s};
            float4 c1 = {acc[i][4] * s, acc[i][5] * s, acc[i][6] * s, acc[i][7] * s};
            *(float4*)&C[(size_t)row * N + n0 + tx * 8] = c0;
            *(float4*)&C[(size_t)row * N + n0 + tx * 8 + 4] = c1;
        }
    }
}

// ---------------- CSR gather v3: 8 independent row loads in flight ----------
__global__ __launch_bounds__(256) void k_gather(
    const float* __restrict__ qs, const int* __restrict__ rowptr,
    const int* __restrict__ csr, const float* __restrict__ dis,
    float* __restrict__ p) {
    int node = blockIdx.x * 4 + (threadIdx.x >> 6);
    if (node >= N_NODES) return;
    int lane = threadIdx.x & 63;
    int beg = rowptr[node], end = rowptr[node + 1];
    float2 acc = *(const float2*)&qs[(size_t)node * 128 + lane * 2];
    int j = beg;
    for (; j + 8 <= end; j += 8) {
        int s0 = csr[j],     s1 = csr[j + 1], s2 = csr[j + 2], s3 = csr[j + 3];
        int s4 = csr[j + 4], s5 = csr[j + 5], s6 = csr[j + 6], s7 = csr[j + 7];
        float2 v0 = *(const float2*)&qs[(size_t)s0 * 128 + lane * 2];
        float2 v1 = *(const float2*)&qs[(size_t)s1 * 128 + lane * 2];
        float2 v2 = *(const float2*)&qs[(size_t)s2 * 128 + lane * 2];
        float2 v3 = *(const float2*)&qs[(size_t)s3 * 128 + lane * 2];
        float2 v4 = *(const float2*)&qs[(size_t)s4 * 128 + lane * 2];
        float2 v5 = *(const float2*)&qs[(size_t)s5 * 128 + lane * 2];
        float2 v6 = *(const float2*)&qs[(size_t)s6 * 128 + lane * 2];
        float2 v7 = *(const float2*)&qs[(size_t)s7 * 128 + lane * 2];
        acc.x += v0.x; acc.y += v0.y;  acc.x += v1.x; acc.y += v1.y;
        acc.x += v2.x; acc.y += v2.y;  acc.x += v3.x; acc.y += v3.y;
        acc.x += v4.x; acc.y += v4.y;  acc.x += v5.x; acc.y += v5.y;
        acc.x += v6.x; acc.y += v6.y;  acc.x += v7.x; acc.y += v7.y;
    }
    for (; j + 4 <= end; j += 4) {
        int s0 = csr[j], s1 = csr[j + 1], s2 = csr[j + 2], s3 = csr[j + 3];
        float2 v0 = *(const float2*)&qs[(size_t)s0 * 128 + lane * 2];
        float2 v1 = *(const float2*)&qs[(size_t)s1 * 128 + lane * 2];
        float2 v2 = *(const float2*)&qs[(size_t)s2 * 128 + lane * 2];
        float2 v3 = *(const float2*)&qs[(size_t)s3 * 128 + lane * 2];
        acc.x += v0.x; acc.y += v0.y;  acc.x += v1.x; acc.y += v1.y;
        acc.x += v2.x; acc.y += v2.y;  acc.x += v3.x; acc.y += v3.y;
    }
    for (; j < end; ++j) {
        int src = csr[j];
        float2 v = *(const float2*)&qs[(size_t)src * 128 + lane * 2];
        acc.x += v.x;
        acc.y += v.y;
    }
    float d = dis[node];
    float2 r = {acc.x * d, acc.y * d};
    *(float2*)&p[(size_t)node * 128 + lane * 2] = r;
}

// ---------------- fused edge MLP v4: W2 pinned in VGPRs, float4 loads -------
// thread (o = lane&31, kh = lane>>5) holds W2[kh*64 + i][o] in 64 PINNED VGPRs
// (asm keeps the compiler from sinking the loads back into the loop — that
// was v2's hidden cost: 64 per-lane global loads per edge).
// Each pass stages 2 edges (half-wave kh owns edge e0+2g+kh, lane covers 4
// columns via float4). Layer2: both staged edges, all 64 lanes, pure
// ds_read_b128 + FMA. No runtime-indexed per-thread arrays (v3 spill lesson).
__global__ __launch_bounds__(256, 4) void k_edge_mlp(
    const float* __restrict__ p, const int* __restrict__ eli,
    const float* __restrict__ b1, const float* __restrict__ W2,
    const float* __restrict__ b2, const float* __restrict__ W3,
    const float* __restrict__ b3, float* __restrict__ out) {
    __shared__ float st[4][2][128];

    const int tid = threadIdx.x;
    const int wave = tid >> 6, lane = tid & 63;
    const int o = lane & 31, kh = lane >> 5;

    float w2r[64];
    #pragma unroll
    for (int i = 0; i < 64; ++i)
        w2r[i] = W2[(kh * 64 + i) * 32 + o];
    #pragma unroll
    for (int i = 0; i < 64; ++i)
        asm volatile("" : "+v"(w2r[i]));  // pin: forces actual VGPR residency

    const float b2r = b2[o];
    const float w3r = W3[o];
    const float b3r = b3[0];
    const float4 bb4 = *(const float4*)&b1[o * 4];

    const int e0 = (blockIdx.x * 4 + wave) * 16;

    #pragma unroll 2
    for (int g = 0; g < 8; ++g) {
        // stage 2 edges: half-wave kh handles edge e0+2g+kh, cols o*4..o*4+3
        const int e = e0 + g * 2 + kh;
        const int src = eli[e];
        const int dst = eli[N_LABEL + e];
        const float4 pd = *(const float4*)&p[(size_t)dst * 128 + o * 4];
        const float4 ps = *(const float4*)&p[(size_t)src * 128 + o * 4];
        float4 tv;
        tv.x = fmaxf(pd.x - ps.x + bb4.x, 0.f);
        tv.y = fmaxf(pd.y - ps.y + bb4.y, 0.f);
        tv.z = fmaxf(pd.z - ps.z + bb4.z, 0.f);
        tv.w = fmaxf(pd.w - ps.w + bb4.w, 0.f);
        *(float4*)&st[wave][kh][o * 4] = tv;
        // same-wave LDS RAW: waitcnt ordering suffices, no barrier

        float acc0 = 0.f, acc1 = 0.f;
        #pragma unroll
        for (int i = 0; i < 64; i += 4) {
            const float4 t0 = *(const float4*)&st[wave][0][kh * 64 + i];
            const float4 t1 = *(const float4*)&st[wave][1][kh * 64 + i];
            acc0 = fmaf(t0.x, w2r[i + 0], acc0);
            acc0 = fmaf(t0.y, w2r[i + 1], acc0);
            acc0 = fmaf(t0.z, w2r[i + 2], acc0);
            acc0 = fmaf(t0.w, w2r[i + 3], acc0);
            acc1 = fmaf(t1.x, w2r[i + 0], acc1);
            acc1 = fmaf(t1.y, w2r[i + 1], acc1);
            acc1 = fmaf(t1.z, w2r[i + 2], acc1);
            acc1 = fmaf(t1.w, w2r[i + 3], acc1);
        }
        float a0 = acc0 + __shfl_xor(acc0, 32);   // merge k-halves (edge A)
        float u0 = fmaxf(a0 + b2r, 0.f) * w3r;
        #pragma unroll
        for (int m = 16; m; m >>= 1) u0 += __shfl_xor(u0, m);
        float a1 = acc1 + __shfl_xor(acc1, 32);   // merge k-halves (edge B)
        float u1 = fmaxf(a1 + b2r, 0.f) * w3r;
        #pragma unroll
        for (int m = 16; m; m >>= 1) u1 += __shfl_xor(u1, m);
        if (lane == 0) {
            out[e0 + g * 2 + 0] = u0 + b3r;
            out[e0 + g * 2 + 1] = u1 + b3r;
        }
    }
}

// ---------------- launch ----------------
extern "C" void kernel_launch(void* const* d_in, const int* in_sizes, int n_in,
                              void* d_out, int out_size, void* d_ws, size_t ws_size,
                              hipStream_t stream) {
    const float* x   = (const float*)d_in[0];
    const int*   ei  = (const int*)d_in[1];
    const int*   eli = (const int*)d_in[2];
    const float* Wg  = (const float*)d_in[3];
    // d_in[4] = b_gcn : cancels in h[dst]-h[src], unused
    const float* W1  = (const float*)d_in[5];
    const float* b1  = (const float*)d_in[6];
    const float* W2  = (const float*)d_in[7];
    const float* b2  = (const float*)d_in[8];
    const float* W3  = (const float*)d_in[9];
    const float* b3  = (const float*)d_in[10];
    float* out = (float*)d_out;

    // ---- workspace layout (bytes), all regions disjoint & 16B-aligned ----
    char* ws = (char*)d_ws;
    float* dis    = (float*)(ws + 0);           // 400 KB
    int*   cnt    = (int*)(ws + 524288);        // 400 KB
    int*   cursor = (int*)(ws + 1048576);       // 400 KB
    int*   rowptr = (int*)(ws + 1572864);       // 400 KB + 4
    int*   bsum   = (int*)(ws + 2000000);       // 512 B (98 ints)
    int*   csr    = (int*)(ws + 2097152);       // 3.2 MB (4 MB reserved)
    float* Wf     = (float*)(ws + 6291456);     // 128 KB
    float* qs     = (float*)(ws + 8388608);     // 51.2 MB
    float* p      = (float*)(ws + 59588608);    // 51.2 MB

    const int NB = (N_NODES + 1023) / 1024;     // 98

    // CSR build + degree norm
    k_zero2<<<(N_NODES + 255) / 256, 256, 0, stream>>>(cnt, cursor);
    k_count<<<(N_EDGES + 255) / 256, 256, 0, stream>>>(ei, cnt);
    k_dis<<<(N_NODES + 255) / 256, 256, 0, stream>>>(cnt, dis);
    k_bsum<<<NB, 1024, 0, stream>>>(cnt, bsum);
    k_bscan<<<1, 128, 0, stream>>>(bsum, NB);
    k_rowptr<<<NB, 1024, 0, stream>>>(cnt, bsum, rowptr);
    k_fill<<<(N_EDGES + 255) / 256, 256, 0, stream>>>(ei, rowptr, cursor, csr);

    // Wf = W_gcn @ W1   [256,256]@[256,128]
    gemm_f32<<<dim3(2, 1), 256, 0, stream>>>(Wg, W1, Wf, 256, 128, 256, nullptr);

    // qs = (x @ Wf) * dis[row]   [100000,256]@[256,128]
    gemm_f32<<<dim3((N_NODES + 127) / 128, 1), 256, 0, stream>>>(
        x, Wf, qs, N_NODES, 128, 256, dis);

    // p[i] = dis[i] * (qs[i] + sum_{src->i} qs[src])
    k_gather<<<(N_NODES + 3) / 4, 256, 0, stream>>>(qs, rowptr, csr, dis, p);

    // fused per-edge MLP: 16 edges/wave, 4 waves/block
    k_edge_mlp<<<N_LABEL / 64, 256, 0, stream>>>(p, eli, b1, W2, b2, W3, b3, out);
}

// Round 9
// 372.662 us; speedup vs baseline: 5.1695x; 1.1616x over previous
//
#include <hip/hip_runtime.h>

#define N_NODES 100000
#define N_EDGES 800000
#define N_LABEL 400000
// IN_CH = 256, OUT_CH = 256, H1 = 128, H2 = 32
// Key algebra: b_gcn cancels in h[dst]-h[src]; h@W1 = S_hat (x @ (W_gcn@W1)).
// So we only ever need p = S_hat(x@Wf) [100k,128], Wf = W_gcn@W1.
// qs GEMM runs on MFMA via split-bf16: C = xh@Wh + xh@Wl + xl@Wh (lo*lo dropped,
// ~2^-18 relative -> abs error ~1e-5, way under the 3.4e-3 threshold).

typedef __attribute__((ext_vector_type(8))) short bf16x8;
typedef __attribute__((ext_vector_type(4))) float f32x4;
typedef unsigned int uint;
typedef unsigned short ushort;

__device__ __forceinline__ ushort f2bf(float f) {  // round-to-nearest-even
    uint u = __float_as_uint(f);
    u += 0x7FFFu + ((u >> 16) & 1u);
    return (ushort)(u >> 16);
}
__device__ __forceinline__ uint pack2(ushort a, ushort b) {
    return (uint)a | ((uint)b << 16);
}

// ---------------- init counters ----------------
__global__ void k_zero2(int* __restrict__ a, int* __restrict__ b) {
    int i = blockIdx.x * 256 + threadIdx.x;
    if (i < N_NODES) { a[i] = 0; b[i] = 0; }
}

__global__ void k_count(const int* __restrict__ ei, int* __restrict__ cnt) {
    int e = blockIdx.x * 256 + threadIdx.x;
    if (e < N_EDGES) atomicAdd(&cnt[ei[N_EDGES + e]], 1);  // dst = ei[1][e]
}

__global__ void k_dis(const int* __restrict__ cnt, float* __restrict__ dis) {
    int i = blockIdx.x * 256 + threadIdx.x;
    if (i < N_NODES) dis[i] = rsqrtf((float)(cnt[i] + 1));  // +1 self loop
}

// ---------------- hierarchical exclusive scan: cnt -> rowptr ----------------
__global__ __launch_bounds__(1024) void k_bsum(const int* __restrict__ cnt,
                                               int* __restrict__ bsum) {
    __shared__ int red[1024];
    int t = threadIdx.x;
    int i = blockIdx.x * 1024 + t;
    red[t] = (i < N_NODES) ? cnt[i] : 0;
    __syncthreads();
    #pragma unroll
    for (int off = 512; off; off >>= 1) {
        if (t < off) red[t] += red[t + off];
        __syncthreads();
    }
    if (t == 0) bsum[blockIdx.x] = red[0];
}

__global__ void k_bscan(int* __restrict__ bsum, int nb) {
    __shared__ int s[128];
    int t = threadIdx.x;
    s[t] = (t < nb) ? bsum[t] : 0;
    __syncthreads();
    #pragma unroll
    for (int off = 1; off < 128; off <<= 1) {
        int v = (t >= off) ? s[t - off] : 0;
        __syncthreads();
        s[t] += v;
        __syncthreads();
    }
    if (t < nb) bsum[t] = t ? s[t - 1] : 0;
}

__global__ __launch_bounds__(1024) void k_rowptr(const int* __restrict__ cnt,
                                                 const int* __restrict__ bsum,
                                                 int* __restrict__ rowptr) {
    __shared__ int s[1024];
    int t = threadIdx.x;
    int i = blockIdx.x * 1024 + t;
    int v = (i < N_NODES) ? cnt[i] : 0;
    s[t] = v;
    __syncthreads();
    #pragma unroll
    for (int off = 1; off < 1024; off <<= 1) {
        int u = (t >= off) ? s[t - off] : 0;
        __syncthreads();
        s[t] += u;
        __syncthreads();
    }
    int excl = s[t] - v + bsum[blockIdx.x];
    if (i < N_NODES) rowptr[i] = excl;
    if (i == N_NODES - 1) rowptr[N_NODES] = excl + v;  // == N_EDGES
}

__global__ void k_fill(const int* __restrict__ ei, const int* __restrict__ rowptr,
                       int* __restrict__ cursor, int* __restrict__ csr) {
    int e = blockIdx.x * 256 + threadIdx.x;
    if (e >= N_EDGES) return;
    int src = ei[e];
    int dst = ei[N_EDGES + e];
    int pos = rowptr[dst] + atomicAdd(&cursor[dst], 1);
    csr[pos] = src;
}

// ---------------- fp32 tiled GEMM (only for tiny Wf = Wg@W1) ----------------
__global__ __launch_bounds__(256) void gemm_f32(
    const float* __restrict__ A, const float* __restrict__ B,
    float* __restrict__ C, int M, int N, int K,
    const float* __restrict__ rowscale) {
    __shared__ float As[2][16][132];
    __shared__ float Bs[2][16][132];

    const int tid = threadIdx.x;
    const int tx = tid & 15, ty = tid >> 4;
    const int m0 = blockIdx.x * 128, n0 = blockIdx.y * 128;

    const int ar = tid >> 2;
    const int ac = (tid & 3) * 4;
    const int bk = tid >> 5;
    const int bc = (tid & 31) * 4;

    float acc[8][8] = {};
    float4 va[2], vb[2];

    auto loadG = [&](int k0) {
        #pragma unroll
        for (int hh = 0; hh < 2; ++hh) {
            int row = m0 + ar + hh * 64;
            va[hh] = make_float4(0.f, 0.f, 0.f, 0.f);
            if (row < M) va[hh] = *(const float4*)&A[(size_t)row * K + k0 + ac];
            vb[hh] = *(const float4*)&B[(size_t)(k0 + bk + hh * 8) * N + n0 + bc];
        }
    };
    auto storeL = [&](int buf) {
        #pragma unroll
        for (int hh = 0; hh < 2; ++hh) {
            As[buf][ac + 0][ar + hh * 64] = va[hh].x;
            As[buf][ac + 1][ar + hh * 64] = va[hh].y;
            As[buf][ac + 2][ar + hh * 64] = va[hh].z;
            As[buf][ac + 3][ar + hh * 64] = va[hh].w;
            *(float4*)&Bs[buf][bk + hh * 8][bc] = vb[hh];
        }
    };

    loadG(0);
    storeL(0);
    __syncthreads();

    int cur = 0;
    for (int k0 = 16;; k0 += 16) {
        const bool last = (k0 >= K);
        if (!last) loadG(k0);

        #pragma unroll
        for (int kk = 0; kk < 16; ++kk) {
            const float4 a0 = *(const float4*)&As[cur][kk][ty * 8];
            const float4 a1 = *(const float4*)&As[cur][kk][ty * 8 + 4];
            const float4 b0 = *(const float4*)&Bs[cur][kk][tx * 8];
            const float4 b1 = *(const float4*)&Bs[cur][kk][tx * 8 + 4];
            const float aa[8] = {a0.x, a0.y, a0.z, a0.w, a1.x, a1.y, a1.z, a1.w};
            const float bb[8] = {b0.x, b0.y, b0.z, b0.w, b1.x, b1.y, b1.z, b1.w};
            #pragma unroll
            for (int i = 0; i < 8; ++i)
                #pragma unroll
                for (int j = 0; j < 8; ++j)
                    acc[i][j] = fmaf(aa[i], bb[j], acc[i][j]);
        }
        if (last) break;
        storeL(cur ^ 1);
        __syncthreads();
        cur ^= 1;
    }

    #pragma unroll
    for (int i = 0; i < 8; ++i) {
        int row = m0 + ty * 8 + i;
        if (row < M) {
            float s = rowscale ? rowscale[row] : 1.0f;
            float4 c0 = {acc[i][0] * s, acc[i][1] * s, acc[i][2] * s, acc[i][3] * s};
            float4 c1 = {acc[i][4] * s, acc[i][5] * s, acc[i][6] * s, acc[i][7] * s};
            *(float4*)&C[(size_t)row * N + n0 + tx * 8] = c0;
            *(float4*)&C[(size_t)row * N + n0 + tx * 8 + 4] = c1;
        }
    }
}

// ---------------- Wf -> bf16 hi/lo, fragment-linear for MFMA B-operand ------
// id -> (s,ct,l,j): B elem k = s*32 + (l>>4)*8 + j, col = ct*16 + (l&15).
__global__ void k_wsplit(const float* __restrict__ Wf, ushort* __restrict__ Bh,
                         ushort* __restrict__ Bl) {
    int id = blockIdx.x * 256 + threadIdx.x;
    if (id >= 32768) return;
    int j = id & 7, l = (id >> 3) & 63, ct = (id >> 9) & 7, s = id >> 12;
    int k = s * 32 + (l >> 4) * 8 + j;
    int col = ct * 16 + (l & 15);
    float w = Wf[k * 128 + col];
    ushort h = f2bf(w);
    float hf = __uint_as_float(((uint)h) << 16);
    ushort lo = f2bf(w - hf);
    Bh[id] = h;
    Bl[id] = lo;
}

// ---------------- MFMA split-bf16 GEMM: qs = (x @ Wf) * dis[row] ------------
// 128x128 block (N=128 full), BK=32, 8 K-steps, 4 waves. Wave w owns rows
// [w*32, w*32+32) = 2 row-tiles x 8 col-tiles of 16x16.
// A frag (16x16x32 bf16): lane holds row=lane&15, k=(lane>>4)*8+j.
// B frag: col=lane&15, k=(lane>>4)*8+j.  D: col=lane&15, row=(lane>>4)*4+reg.
// LDS is fragment-linear: slot(rt,l) = rt*64+l, 8 bf16 each -> conflict-free
// 16B lane reads. x converted in-kernel (f32 -> hi/lo bf16).
__global__ __launch_bounds__(256) void gemm_mfma(
    const float* __restrict__ x, const ushort* __restrict__ Bh,
    const ushort* __restrict__ Bl, const float* __restrict__ dis,
    float* __restrict__ qs) {
    __shared__ __align__(16) ushort Ah[4096], Al[4096], Bhs[4096], Bls[4096];

    const int tid = threadIdx.x;
    const int w = tid >> 6, lane = tid & 63;
    const int m0 = blockIdx.x * 128;
    const int srow = tid >> 3;   // 0..31: row within 32-row staging pass
    const int skq = tid & 7;     // k-quad: covers k = skq*4 .. skq*4+3

    f32x4 acc[2][8];
    #pragma unroll
    for (int i = 0; i < 2; ++i)
        #pragma unroll
        for (int j = 0; j < 8; ++j)
            acc[i][j] = (f32x4){0.f, 0.f, 0.f, 0.f};

    float4 r0, r1, r2, r3;       // x prefetch: pass p covers rows p*32+srow
    uint4 pb0, pb1, pc0, pc1;    // B prefetch (hi: pb, lo: pc)

    auto xload = [&](int s) {
        const int kc = s * 32 + skq * 4;
        int row;
        const float4 z = make_float4(0.f, 0.f, 0.f, 0.f);
        row = m0 + srow;       r0 = (row < N_NODES) ? *(const float4*)&x[(size_t)row * 256 + kc] : z;
        row = m0 + 32 + srow;  r1 = (row < N_NODES) ? *(const float4*)&x[(size_t)row * 256 + kc] : z;
        row = m0 + 64 + srow;  r2 = (row < N_NODES) ? *(const float4*)&x[(size_t)row * 256 + kc] : z;
        row = m0 + 96 + srow;  r3 = (row < N_NODES) ? *(const float4*)&x[(size_t)row * 256 + kc] : z;
    };
    auto bload = [&](int s) {
        const uint4* ph = (const uint4*)(Bh + s * 4096);
        const uint4* pl = (const uint4*)(Bl + s * 4096);
        pb0 = ph[tid * 2]; pb1 = ph[tid * 2 + 1];
        pc0 = pl[tid * 2]; pc1 = pl[tid * 2 + 1];
    };
    // stage one pass: reg v holds x[p*32+srow][k = skq*4 + 0..3]
    auto stageA = [&](int p, const float4& v) {
        // frag addr: slot = (row>>4)*64 + (k>>3)*16 + (row&15); off = slot*8 + (k&4)
        const int off = ((p * 2 + (srow >> 4)) * 64 + (skq >> 1) * 16 + (srow & 15)) * 8
                        + (skq & 1) * 4;
        ushort h0 = f2bf(v.x), h1 = f2bf(v.y), h2 = f2bf(v.z), h3 = f2bf(v.w);
        *(uint2*)&Ah[off] = make_uint2(pack2(h0, h1), pack2(h2, h3));
        float l0 = v.x - __uint_as_float(((uint)h0) << 16);
        float l1 = v.y - __uint_as_float(((uint)h1) << 16);
        float l2 = v.z - __uint_as_float(((uint)h2) << 16);
        float l3 = v.w - __uint_as_float(((uint)h3) << 16);
        *(uint2*)&Al[off] = make_uint2(pack2(f2bf(l0), f2bf(l1)),
                                       pack2(f2bf(l2), f2bf(l3)));
    };

    xload(0);
    bload(0);

    for (int s = 0; s < 8; ++s) {
        if (s) __syncthreads();          // prev step's MFMA reads done
        stageA(0, r0); stageA(1, r1); stageA(2, r2); stageA(3, r3);
        *(uint4*)&Bhs[tid * 16] = pb0; *(uint4*)&Bhs[tid * 16 + 8] = pb1;
        *(uint4*)&Bls[tid * 16] = pc0; *(uint4*)&Bls[tid * 16 + 8] = pc1;
        if (s < 7) { xload(s + 1); bload(s + 1); }   // fire-and-forget
        __syncthreads();                 // staging visible

        const bf16x8 ah0 = *(const bf16x8*)&Ah[((w * 2 + 0) * 64 + lane) * 8];
        const bf16x8 al0 = *(const bf16x8*)&Al[((w * 2 + 0) * 64 + lane) * 8];
        const bf16x8 ah1 = *(const bf16x8*)&Ah[((w * 2 + 1) * 64 + lane) * 8];
        const bf16x8 al1 = *(const bf16x8*)&Al[((w * 2 + 1) * 64 + lane) * 8];
        #pragma unroll
        for (int ct = 0; ct < 8; ++ct) {
            const bf16x8 bh = *(const bf16x8*)&Bhs[(ct * 64 + lane) * 8];
            const bf16x8 bl = *(const bf16x8*)&Bls[(ct * 64 + lane) * 8];
            acc[0][ct] = __builtin_amdgcn_mfma_f32_16x16x32_bf16(al0, bh, acc[0][ct], 0, 0, 0);
            acc[0][ct] = __builtin_amdgcn_mfma_f32_16x16x32_bf16(ah0, bl, acc[0][ct], 0, 0, 0);
            acc[0][ct] = __builtin_amdgcn_mfma_f32_16x16x32_bf16(ah0, bh, acc[0][ct], 0, 0, 0);
            acc[1][ct] = __builtin_amdgcn_mfma_f32_16x16x32_bf16(al1, bh, acc[1][ct], 0, 0, 0);
            acc[1][ct] = __builtin_amdgcn_mfma_f32_16x16x32_bf16(ah1, bl, acc[1][ct], 0, 0, 0);
            acc[1][ct] = __builtin_amdgcn_mfma_f32_16x16x32_bf16(ah1, bh, acc[1][ct], 0, 0, 0);
        }
    }

    // epilogue: row-scale by dis, store. D elem (reg j): row=(lane>>4)*4+j, col=lane&15
    #pragma unroll
    for (int rt = 0; rt < 2; ++rt) {
        #pragma unroll
        for (int j = 0; j < 4; ++j) {
            const int row = m0 + w * 32 + rt * 16 + (lane >> 4) * 4 + j;
            if (row < N_NODES) {
                const float sc = dis[row];
                #pragma unroll
                for (int ct = 0; ct < 8; ++ct)
                    qs[(size_t)row * 128 + ct * 16 + (lane & 15)] = acc[rt][ct][j] * sc;
            }
        }
    }
}

// ---------------- CSR gather v3: 8 independent row loads in flight ----------
__global__ __launch_bounds__(256) void k_gather(
    const float* __restrict__ qs, const int* __restrict__ rowptr,
    const int* __restrict__ csr, const float* __restrict__ dis,
    float* __restrict__ p) {
    int node = blockIdx.x * 4 + (threadIdx.x >> 6);
    if (node >= N_NODES) return;
    int lane = threadIdx.x & 63;
    int beg = rowptr[node], end = rowptr[node + 1];
    float2 acc = *(const float2*)&qs[(size_t)node * 128 + lane * 2];
    int j = beg;
    for (; j + 8 <= end; j += 8) {
        int s0 = csr[j],     s1 = csr[j + 1], s2 = csr[j + 2], s3 = csr[j + 3];
        int s4 = csr[j + 4], s5 = csr[j + 5], s6 = csr[j + 6], s7 = csr[j + 7];
        float2 v0 = *(const float2*)&qs[(size_t)s0 * 128 + lane * 2];
        float2 v1 = *(const float2*)&qs[(size_t)s1 * 128 + lane * 2];
        float2 v2 = *(const float2*)&qs[(size_t)s2 * 128 + lane * 2];
        float2 v3 = *(const float2*)&qs[(size_t)s3 * 128 + lane * 2];
        float2 v4 = *(const float2*)&qs[(size_t)s4 * 128 + lane * 2];
        float2 v5 = *(const float2*)&qs[(size_t)s5 * 128 + lane * 2];
        float2 v6 = *(const float2*)&qs[(size_t)s6 * 128 + lane * 2];
        float2 v7 = *(const float2*)&qs[(size_t)s7 * 128 + lane * 2];
        acc.x += v0.x; acc.y += v0.y;  acc.x += v1.x; acc.y += v1.y;
        acc.x += v2.x; acc.y += v2.y;  acc.x += v3.x; acc.y += v3.y;
        acc.x += v4.x; acc.y += v4.y;  acc.x += v5.x; acc.y += v5.y;
        acc.x += v6.x; acc.y += v6.y;  acc.x += v7.x; acc.y += v7.y;
    }
    for (; j + 4 <= end; j += 4) {
        int s0 = csr[j], s1 = csr[j + 1], s2 = csr[j + 2], s3 = csr[j + 3];
        float2 v0 = *(const float2*)&qs[(size_t)s0 * 128 + lane * 2];
        float2 v1 = *(const float2*)&qs[(size_t)s1 * 128 + lane * 2];
        float2 v2 = *(const float2*)&qs[(size_t)s2 * 128 + lane * 2];
        float2 v3 = *(const float2*)&qs[(size_t)s3 * 128 + lane * 2];
        acc.x += v0.x; acc.y += v0.y;  acc.x += v1.x; acc.y += v1.y;
        acc.x += v2.x; acc.y += v2.y;  acc.x += v3.x; acc.y += v3.y;
    }
    for (; j < end; ++j) {
        int src = csr[j];
        float2 v = *(const float2*)&qs[(size_t)src * 128 + lane * 2];
        acc.x += v.x;
        acc.y += v.y;
    }
    float d = dis[node];
    float2 r = {acc.x * d, acc.y * d};
    *(float2*)&p[(size_t)node * 128 + lane * 2] = r;
}

// ---------------- fused edge MLP v4: W2 pinned in VGPRs, float4 loads -------
__global__ __launch_bounds__(256, 4) void k_edge_mlp(
    const float* __restrict__ p, const int* __restrict__ eli,
    const float* __restrict__ b1, const float* __restrict__ W2,
    const float* __restrict__ b2, const float* __restrict__ W3,
    const float* __restrict__ b3, float* __restrict__ out) {
    __shared__ float st[4][2][128];

    const int tid = threadIdx.x;
    const int wave = tid >> 6, lane = tid & 63;
    const int o = lane & 31, kh = lane >> 5;

    float w2r[64];
    #pragma unroll
    for (int i = 0; i < 64; ++i)
        w2r[i] = W2[(kh * 64 + i) * 32 + o];
    #pragma unroll
    for (int i = 0; i < 64; ++i)
        asm volatile("" : "+v"(w2r[i]));  // pin: forces actual VGPR residency

    const float b2r = b2[o];
    const float w3r = W3[o];
    const float b3r = b3[0];
    const float4 bb4 = *(const float4*)&b1[o * 4];

    const int e0 = (blockIdx.x * 4 + wave) * 16;

    #pragma unroll 2
    for (int g = 0; g < 8; ++g) {
        const int e = e0 + g * 2 + kh;
        const int src = eli[e];
        const int dst = eli[N_LABEL + e];
        const float4 pd = *(const float4*)&p[(size_t)dst * 128 + o * 4];
        const float4 ps = *(const float4*)&p[(size_t)src * 128 + o * 4];
        float4 tv;
        tv.x = fmaxf(pd.x - ps.x + bb4.x, 0.f);
        tv.y = fmaxf(pd.y - ps.y + bb4.y, 0.f);
        tv.z = fmaxf(pd.z - ps.z + bb4.z, 0.f);
        tv.w = fmaxf(pd.w - ps.w + bb4.w, 0.f);
        *(float4*)&st[wave][kh][o * 4] = tv;

        float acc0 = 0.f, acc1 = 0.f;
        #pragma unroll
        for (int i = 0; i < 64; i += 4) {
            const float4 t0 = *(const float4*)&st[wave][0][kh * 64 + i];
            const float4 t1 = *(const float4*)&st[wave][1][kh * 64 + i];
            acc0 = fmaf(t0.x, w2r[i + 0], acc0);
            acc0 = fmaf(t0.y, w2r[i + 1], acc0);
            acc0 = fmaf(t0.z, w2r[i + 2], acc0);
            acc0 = fmaf(t0.w, w2r[i + 3], acc0);
            acc1 = fmaf(t1.x, w2r[i + 0], acc1);
            acc1 = fmaf(t1.y, w2r[i + 1], acc1);
            acc1 = fmaf(t1.z, w2r[i + 2], acc1);
            acc1 = fmaf(t1.w, w2r[i + 3], acc1);
        }
        float a0 = acc0 + __shfl_xor(acc0, 32);
        float u0 = fmaxf(a0 + b2r, 0.f) * w3r;
        #pragma unroll
        for (int m = 16; m; m >>= 1) u0 += __shfl_xor(u0, m);
        float a1 = acc1 + __shfl_xor(acc1, 32);
        float u1 = fmaxf(a1 + b2r, 0.f) * w3r;
        #pragma unroll
        for (int m = 16; m; m >>= 1) u1 += __shfl_xor(u1, m);
        if (lane == 0) {
            out[e0 + g * 2 + 0] = u0 + b3r;
            out[e0 + g * 2 + 1] = u1 + b3r;
        }
    }
}

// ---------------- launch ----------------
extern "C" void kernel_launch(void* const* d_in, const int* in_sizes, int n_in,
                              void* d_out, int out_size, void* d_ws, size_t ws_size,
                              hipStream_t stream) {
    const float* x   = (const float*)d_in[0];
    const int*   ei  = (const int*)d_in[1];
    const int*   eli = (const int*)d_in[2];
    const float* Wg  = (const float*)d_in[3];
    // d_in[4] = b_gcn : cancels in h[dst]-h[src], unused
    const float* W1  = (const float*)d_in[5];
    const float* b1  = (const float*)d_in[6];
    const float* W2  = (const float*)d_in[7];
    const float* b2  = (const float*)d_in[8];
    const float* W3  = (const float*)d_in[9];
    const float* b3  = (const float*)d_in[10];
    float* out = (float*)d_out;

    // ---- workspace layout (bytes), all regions disjoint & 16B-aligned ----
    char* ws = (char*)d_ws;
    float*  dis    = (float*)(ws + 0);           // 400 KB
    int*    cnt    = (int*)(ws + 524288);        // 400 KB
    int*    cursor = (int*)(ws + 1048576);       // 400 KB
    int*    rowptr = (int*)(ws + 1572864);       // 400 KB + 4
    int*    bsum   = (int*)(ws + 2000000);       // 512 B (98 ints)
    int*    csr    = (int*)(ws + 2097152);       // 3.2 MB (4 MB reserved)
    float*  Wf     = (float*)(ws + 6291456);     // 128 KB
    ushort* Bh     = (ushort*)(ws + 6422528);    // 64 KB
    ushort* Bl     = (ushort*)(ws + 6488064);    // 64 KB
    float*  qs     = (float*)(ws + 8388608);     // 51.2 MB
    float*  p      = (float*)(ws + 59588608);    // 51.2 MB

    const int NB = (N_NODES + 1023) / 1024;      // 98

    // CSR build + degree norm
    k_zero2<<<(N_NODES + 255) / 256, 256, 0, stream>>>(cnt, cursor);
    k_count<<<(N_EDGES + 255) / 256, 256, 0, stream>>>(ei, cnt);
    k_dis<<<(N_NODES + 255) / 256, 256, 0, stream>>>(cnt, dis);
    k_bsum<<<NB, 1024, 0, stream>>>(cnt, bsum);
    k_bscan<<<1, 128, 0, stream>>>(bsum, NB);
    k_rowptr<<<NB, 1024, 0, stream>>>(cnt, bsum, rowptr);
    k_fill<<<(N_EDGES + 255) / 256, 256, 0, stream>>>(ei, rowptr, cursor, csr);

    // Wf = W_gcn @ W1   [256,256]@[256,128]  (tiny, stays fp32)
    gemm_f32<<<dim3(2, 1), 256, 0, stream>>>(Wg, W1, Wf, 256, 128, 256, nullptr);

    // Wf -> bf16 hi/lo fragment-linear
    k_wsplit<<<128, 256, 0, stream>>>(Wf, Bh, Bl);

    // qs = (x @ Wf) * dis[row]  via split-bf16 MFMA
    gemm_mfma<<<(N_NODES + 127) / 128, 256, 0, stream>>>(x, Bh, Bl, dis, qs);

    // p[i] = dis[i] * (qs[i] + sum_{src->i} qs[src])
    k_gather<<<(N_NODES + 3) / 4, 256, 0, stream>>>(qs, rowptr, csr, dis, p);

    // fused per-edge MLP: 16 edges/wave, 4 waves/block
    k_edge_mlp<<<N_LABEL / 64, 256, 0, stream>>>(p, eli, b1, W2, b2, W3, b3, out);
}

// Round 10
// 336.358 us; speedup vs baseline: 5.7274x; 1.1079x over previous
//
#include <hip/hip_runtime.h>

#define N_NODES 100000
#define N_EDGES 800000
#define N_LABEL 400000
// IN_CH = 256, OUT_CH = 256, H1 = 128, H2 = 32
// Key algebra: b_gcn cancels in h[dst]-h[src]; h@W1 = S_hat (x @ (W_gcn@W1)).
// So we only ever need p = S_hat(x@Wf) [100k,128], Wf = W_gcn@W1.
// qs GEMM runs on MFMA via split-bf16: C = xh@Wh + xh@Wl + xl@Wh (lo*lo dropped,
// ~2^-18 relative -> abs error ~1e-5, way under the 3.4e-3 threshold).

typedef __attribute__((ext_vector_type(8))) short bf16x8;
typedef __attribute__((ext_vector_type(4))) float f32x4;
typedef unsigned int uint;
typedef unsigned short ushort;

__device__ __forceinline__ ushort f2bf(float f) {  // round-to-nearest-even
    uint u = __float_as_uint(f);
    u += 0x7FFFu + ((u >> 16) & 1u);
    return (ushort)(u >> 16);
}
__device__ __forceinline__ uint pack2(ushort a, ushort b) {
    return (uint)a | ((uint)b << 16);
}

// ---------------- init counters ----------------
__global__ void k_zero2(int* __restrict__ a, int* __restrict__ b) {
    int i = blockIdx.x * 256 + threadIdx.x;
    if (i < N_NODES) { a[i] = 0; b[i] = 0; }
}

__global__ void k_count(const int* __restrict__ ei, int* __restrict__ cnt) {
    int e = blockIdx.x * 256 + threadIdx.x;
    if (e < N_EDGES) atomicAdd(&cnt[ei[N_EDGES + e]], 1);  // dst = ei[1][e]
}

__global__ void k_dis(const int* __restrict__ cnt, float* __restrict__ dis) {
    int i = blockIdx.x * 256 + threadIdx.x;
    if (i < N_NODES) dis[i] = rsqrtf((float)(cnt[i] + 1));  // +1 self loop
}

// ---------------- hierarchical exclusive scan: cnt -> rowptr ----------------
__global__ __launch_bounds__(1024) void k_bsum(const int* __restrict__ cnt,
                                               int* __restrict__ bsum) {
    __shared__ int red[1024];
    int t = threadIdx.x;
    int i = blockIdx.x * 1024 + t;
    red[t] = (i < N_NODES) ? cnt[i] : 0;
    __syncthreads();
    #pragma unroll
    for (int off = 512; off; off >>= 1) {
        if (t < off) red[t] += red[t + off];
        __syncthreads();
    }
    if (t == 0) bsum[blockIdx.x] = red[0];
}

__global__ void k_bscan(int* __restrict__ bsum, int nb) {
    __shared__ int s[128];
    int t = threadIdx.x;
    s[t] = (t < nb) ? bsum[t] : 0;
    __syncthreads();
    #pragma unroll
    for (int off = 1; off < 128; off <<= 1) {
        int v = (t >= off) ? s[t - off] : 0;
        __syncthreads();
        s[t] += v;
        __syncthreads();
    }
    if (t < nb) bsum[t] = t ? s[t - 1] : 0;
}

__global__ __launch_bounds__(1024) void k_rowptr(const int* __restrict__ cnt,
                                                 const int* __restrict__ bsum,
                                                 int* __restrict__ rowptr) {
    __shared__ int s[1024];
    int t = threadIdx.x;
    int i = blockIdx.x * 1024 + t;
    int v = (i < N_NODES) ? cnt[i] : 0;
    s[t] = v;
    __syncthreads();
    #pragma unroll
    for (int off = 1; off < 1024; off <<= 1) {
        int u = (t >= off) ? s[t - off] : 0;
        __syncthreads();
        s[t] += u;
        __syncthreads();
    }
    int excl = s[t] - v + bsum[blockIdx.x];
    if (i < N_NODES) rowptr[i] = excl;
    if (i == N_NODES - 1) rowptr[N_NODES] = excl + v;  // == N_EDGES
}

__global__ void k_fill(const int* __restrict__ ei, const int* __restrict__ rowptr,
                       int* __restrict__ cursor, int* __restrict__ csr) {
    int e = blockIdx.x * 256 + threadIdx.x;
    if (e >= N_EDGES) return;
    int src = ei[e];
    int dst = ei[N_EDGES + e];
    int pos = rowptr[dst] + atomicAdd(&cursor[dst], 1);
    csr[pos] = src;
}

// ---------------- fp32 tiled GEMM (only for tiny Wf = Wg@W1) ----------------
__global__ __launch_bounds__(256) void gemm_f32(
    const float* __restrict__ A, const float* __restrict__ B,
    float* __restrict__ C, int M, int N, int K,
    const float* __restrict__ rowscale) {
    __shared__ float As[2][16][132];
    __shared__ float Bs[2][16][132];

    const int tid = threadIdx.x;
    const int tx = tid & 15, ty = tid >> 4;
    const int m0 = blockIdx.x * 128, n0 = blockIdx.y * 128;

    const int ar = tid >> 2;
    const int ac = (tid & 3) * 4;
    const int bk = tid >> 5;
    const int bc = (tid & 31) * 4;

    float acc[8][8] = {};
    float4 va[2], vb[2];

    auto loadG = [&](int k0) {
        #pragma unroll
        for (int hh = 0; hh < 2; ++hh) {
            int row = m0 + ar + hh * 64;
            va[hh] = make_float4(0.f, 0.f, 0.f, 0.f);
            if (row < M) va[hh] = *(const float4*)&A[(size_t)row * K + k0 + ac];
            vb[hh] = *(const float4*)&B[(size_t)(k0 + bk + hh * 8) * N + n0 + bc];
        }
    };
    auto storeL = [&](int buf) {
        #pragma unroll
        for (int hh = 0; hh < 2; ++hh) {
            As[buf][ac + 0][ar + hh * 64] = va[hh].x;
            As[buf][ac + 1][ar + hh * 64] = va[hh].y;
            As[buf][ac + 2][ar + hh * 64] = va[hh].z;
            As[buf][ac + 3][ar + hh * 64] = va[hh].w;
            *(float4*)&Bs[buf][bk + hh * 8][bc] = vb[hh];
        }
    };

    loadG(0);
    storeL(0);
    __syncthreads();

    int cur = 0;
    for (int k0 = 16;; k0 += 16) {
        const bool last = (k0 >= K);
        if (!last) loadG(k0);

        #pragma unroll
        for (int kk = 0; kk < 16; ++kk) {
            const float4 a0 = *(const float4*)&As[cur][kk][ty * 8];
            const float4 a1 = *(const float4*)&As[cur][kk][ty * 8 + 4];
            const float4 b0 = *(const float4*)&Bs[cur][kk][tx * 8];
            const float4 b1 = *(const float4*)&Bs[cur][kk][tx * 8 + 4];
            const float aa[8] = {a0.x, a0.y, a0.z, a0.w, a1.x, a1.y, a1.z, a1.w};
            const float bb[8] = {b0.x, b0.y, b0.z, b0.w, b1.x, b1.y, b1.z, b1.w};
            #pragma unroll
            for (int i = 0; i < 8; ++i)
                #pragma unroll
                for (int j = 0; j < 8; ++j)
                    acc[i][j] = fmaf(aa[i], bb[j], acc[i][j]);
        }
        if (last) break;
        storeL(cur ^ 1);
        __syncthreads();
        cur ^= 1;
    }

    #pragma unroll
    for (int i = 0; i < 8; ++i) {
        int row = m0 + ty * 8 + i;
        if (row < M) {
            float s = rowscale ? rowscale[row] : 1.0f;
            float4 c0 = {acc[i][0] * s, acc[i][1] * s, acc[i][2] * s, acc[i][3] * s};
            float4 c1 = {acc[i][4] * s, acc[i][5] * s, acc[i][6] * s, acc[i][7] * s};
            *(float4*)&C[(size_t)row * N + n0 + tx * 8] = c0;
            *(float4*)&C[(size_t)row * N + n0 + tx * 8 + 4] = c1;
        }
    }
}

// ---------------- Wf -> bf16 hi/lo, fragment-linear for MFMA B-operand ------
__global__ void k_wsplit(const float* __restrict__ Wf, ushort* __restrict__ Bh,
                         ushort* __restrict__ Bl) {
    int id = blockIdx.x * 256 + threadIdx.x;
    if (id >= 32768) return;
    int j = id & 7, l = (id >> 3) & 63, ct = (id >> 9) & 7, s = id >> 12;
    int k = s * 32 + (l >> 4) * 8 + j;
    int col = ct * 16 + (l & 15);
    float w = Wf[k * 128 + col];
    ushort h = f2bf(w);
    float hf = __uint_as_float(((uint)h) << 16);
    ushort lo = f2bf(w - hf);
    Bh[id] = h;
    Bl[id] = lo;
}

// ---------------- MFMA split-bf16 GEMM: qs = (x @ Wf) * dis[row] ------------
__global__ __launch_bounds__(256) void gemm_mfma(
    const float* __restrict__ x, const ushort* __restrict__ Bh,
    const ushort* __restrict__ Bl, const float* __restrict__ dis,
    float* __restrict__ qs) {
    __shared__ __align__(16) ushort Ah[4096], Al[4096], Bhs[4096], Bls[4096];

    const int tid = threadIdx.x;
    const int w = tid >> 6, lane = tid & 63;
    const int m0 = blockIdx.x * 128;
    const int srow = tid >> 3;   // 0..31: row within 32-row staging pass
    const int skq = tid & 7;     // k-quad: covers k = skq*4 .. skq*4+3

    f32x4 acc[2][8];
    #pragma unroll
    for (int i = 0; i < 2; ++i)
        #pragma unroll
        for (int j = 0; j < 8; ++j)
            acc[i][j] = (f32x4){0.f, 0.f, 0.f, 0.f};

    float4 r0, r1, r2, r3;       // x prefetch: pass p covers rows p*32+srow
    uint4 pb0, pb1, pc0, pc1;    // B prefetch (hi: pb, lo: pc)

    auto xload = [&](int s) {
        const int kc = s * 32 + skq * 4;
        int row;
        const float4 z = make_float4(0.f, 0.f, 0.f, 0.f);
        row = m0 + srow;       r0 = (row < N_NODES) ? *(const float4*)&x[(size_t)row * 256 + kc] : z;
        row = m0 + 32 + srow;  r1 = (row < N_NODES) ? *(const float4*)&x[(size_t)row * 256 + kc] : z;
        row = m0 + 64 + srow;  r2 = (row < N_NODES) ? *(const float4*)&x[(size_t)row * 256 + kc] : z;
        row = m0 + 96 + srow;  r3 = (row < N_NODES) ? *(const float4*)&x[(size_t)row * 256 + kc] : z;
    };
    auto bload = [&](int s) {
        const uint4* ph = (const uint4*)(Bh + s * 4096);
        const uint4* pl = (const uint4*)(Bl + s * 4096);
        pb0 = ph[tid * 2]; pb1 = ph[tid * 2 + 1];
        pc0 = pl[tid * 2]; pc1 = pl[tid * 2 + 1];
    };
    auto stageA = [&](int p, const float4& v) {
        const int off = ((p * 2 + (srow >> 4)) * 64 + (skq >> 1) * 16 + (srow & 15)) * 8
                        + (skq & 1) * 4;
        ushort h0 = f2bf(v.x), h1 = f2bf(v.y), h2 = f2bf(v.z), h3 = f2bf(v.w);
        *(uint2*)&Ah[off] = make_uint2(pack2(h0, h1), pack2(h2, h3));
        float l0 = v.x - __uint_as_float(((uint)h0) << 16);
        float l1 = v.y - __uint_as_float(((uint)h1) << 16);
        float l2 = v.z - __uint_as_float(((uint)h2) << 16);
        float l3 = v.w - __uint_as_float(((uint)h3) << 16);
        *(uint2*)&Al[off] = make_uint2(pack2(f2bf(l0), f2bf(l1)),
                                       pack2(f2bf(l2), f2bf(l3)));
    };

    xload(0);
    bload(0);

    for (int s = 0; s < 8; ++s) {
        if (s) __syncthreads();
        stageA(0, r0); stageA(1, r1); stageA(2, r2); stageA(3, r3);
        *(uint4*)&Bhs[tid * 16] = pb0; *(uint4*)&Bhs[tid * 16 + 8] = pb1;
        *(uint4*)&Bls[tid * 16] = pc0; *(uint4*)&Bls[tid * 16 + 8] = pc1;
        if (s < 7) { xload(s + 1); bload(s + 1); }
        __syncthreads();

        const bf16x8 ah0 = *(const bf16x8*)&Ah[((w * 2 + 0) * 64 + lane) * 8];
        const bf16x8 al0 = *(const bf16x8*)&Al[((w * 2 + 0) * 64 + lane) * 8];
        const bf16x8 ah1 = *(const bf16x8*)&Ah[((w * 2 + 1) * 64 + lane) * 8];
        const bf16x8 al1 = *(const bf16x8*)&Al[((w * 2 + 1) * 64 + lane) * 8];
        #pragma unroll
        for (int ct = 0; ct < 8; ++ct) {
            const bf16x8 bh = *(const bf16x8*)&Bhs[(ct * 64 + lane) * 8];
            const bf16x8 bl = *(const bf16x8*)&Bls[(ct * 64 + lane) * 8];
            acc[0][ct] = __builtin_amdgcn_mfma_f32_16x16x32_bf16(al0, bh, acc[0][ct], 0, 0, 0);
            acc[0][ct] = __builtin_amdgcn_mfma_f32_16x16x32_bf16(ah0, bl, acc[0][ct], 0, 0, 0);
            acc[0][ct] = __builtin_amdgcn_mfma_f32_16x16x32_bf16(ah0, bh, acc[0][ct], 0, 0, 0);
            acc[1][ct] = __builtin_amdgcn_mfma_f32_16x16x32_bf16(al1, bh, acc[1][ct], 0, 0, 0);
            acc[1][ct] = __builtin_amdgcn_mfma_f32_16x16x32_bf16(ah1, bl, acc[1][ct], 0, 0, 0);
            acc[1][ct] = __builtin_amdgcn_mfma_f32_16x16x32_bf16(ah1, bh, acc[1][ct], 0, 0, 0);
        }
    }

    #pragma unroll
    for (int rt = 0; rt < 2; ++rt) {
        #pragma unroll
        for (int j = 0; j < 4; ++j) {
            const int row = m0 + w * 32 + rt * 16 + (lane >> 4) * 4 + j;
            if (row < N_NODES) {
                const float sc = dis[row];
                #pragma unroll
                for (int ct = 0; ct < 8; ++ct)
                    qs[(size_t)row * 128 + ct * 16 + (lane & 15)] = acc[rt][ct][j] * sc;
            }
        }
    }
}

// ---------------- CSR gather v3: 8 independent row loads in flight ----------
__global__ __launch_bounds__(256) void k_gather(
    const float* __restrict__ qs, const int* __restrict__ rowptr,
    const int* __restrict__ csr, const float* __restrict__ dis,
    float* __restrict__ p) {
    int node = blockIdx.x * 4 + (threadIdx.x >> 6);
    if (node >= N_NODES) return;
    int lane = threadIdx.x & 63;
    int beg = rowptr[node], end = rowptr[node + 1];
    float2 acc = *(const float2*)&qs[(size_t)node * 128 + lane * 2];
    int j = beg;
    for (; j + 8 <= end; j += 8) {
        int s0 = csr[j],     s1 = csr[j + 1], s2 = csr[j + 2], s3 = csr[j + 3];
        int s4 = csr[j + 4], s5 = csr[j + 5], s6 = csr[j + 6], s7 = csr[j + 7];
        float2 v0 = *(const float2*)&qs[(size_t)s0 * 128 + lane * 2];
        float2 v1 = *(const float2*)&qs[(size_t)s1 * 128 + lane * 2];
        float2 v2 = *(const float2*)&qs[(size_t)s2 * 128 + lane * 2];
        float2 v3 = *(const float2*)&qs[(size_t)s3 * 128 + lane * 2];
        float2 v4 = *(const float2*)&qs[(size_t)s4 * 128 + lane * 2];
        float2 v5 = *(const float2*)&qs[(size_t)s5 * 128 + lane * 2];
        float2 v6 = *(const float2*)&qs[(size_t)s6 * 128 + lane * 2];
        float2 v7 = *(const float2*)&qs[(size_t)s7 * 128 + lane * 2];
        acc.x += v0.x; acc.y += v0.y;  acc.x += v1.x; acc.y += v1.y;
        acc.x += v2.x; acc.y += v2.y;  acc.x += v3.x; acc.y += v3.y;
        acc.x += v4.x; acc.y += v4.y;  acc.x += v5.x; acc.y += v5.y;
        acc.x += v6.x; acc.y += v6.y;  acc.x += v7.x; acc.y += v7.y;
    }
    for (; j + 4 <= end; j += 4) {
        int s0 = csr[j], s1 = csr[j + 1], s2 = csr[j + 2], s3 = csr[j + 3];
        float2 v0 = *(const float2*)&qs[(size_t)s0 * 128 + lane * 2];
        float2 v1 = *(const float2*)&qs[(size_t)s1 * 128 + lane * 2];
        float2 v2 = *(const float2*)&qs[(size_t)s2 * 128 + lane * 2];
        float2 v3 = *(const float2*)&qs[(size_t)s3 * 128 + lane * 2];
        acc.x += v0.x; acc.y += v0.y;  acc.x += v1.x; acc.y += v1.y;
        acc.x += v2.x; acc.y += v2.y;  acc.x += v3.x; acc.y += v3.y;
    }
    for (; j < end; ++j) {
        int src = csr[j];
        float2 v = *(const float2*)&qs[(size_t)src * 128 + lane * 2];
        acc.x += v.x;
        acc.y += v.y;
    }
    float d = dis[node];
    float2 r = {acc.x * d, acc.y * d};
    *(float2*)&p[(size_t)node * 128 + lane * 2] = r;
}

// ---------------- fused edge MLP v5: v4 + named-reg software pipeline -------
// Same as v4 (W2 pinned, 2 edges per pass) but the p-row loads for pass g+1
// are issued BEFORE layer2 of pass g (named float4 regs npd/nps — NO arrays,
// v3 spill lesson), hiding the eli->p dependent-load chain under ~400cy of
// layer2 compute. Epilogue pass has no prefetch.
__global__ __launch_bounds__(256, 4) void k_edge_mlp(
    const float* __restrict__ p, const int* __restrict__ eli,
    const float* __restrict__ b1, const float* __restrict__ W2,
    const float* __restrict__ b2, const float* __restrict__ W3,
    const float* __restrict__ b3, float* __restrict__ out) {
    __shared__ float st[4][2][128];

    const int tid = threadIdx.x;
    const int wave = tid >> 6, lane = tid & 63;
    const int o = lane & 31, kh = lane >> 5;

    float w2r[64];
    #pragma unroll
    for (int i = 0; i < 64; ++i)
        w2r[i] = W2[(kh * 64 + i) * 32 + o];
    #pragma unroll
    for (int i = 0; i < 64; ++i)
        asm volatile("" : "+v"(w2r[i]));  // pin: forces actual VGPR residency

    const float b2r = b2[o];
    const float w3r = W3[o];
    const float b3r = b3[0];
    const float4 bb4 = *(const float4*)&b1[o * 4];

    const int e0 = (blockIdx.x * 4 + wave) * 16;

    // stage layer1 of current pass into LDS (same-wave RAW, no barrier)
    float4 pd, ps;
    auto stage = [&]() {
        float4 tv;
        tv.x = fmaxf(pd.x - ps.x + bb4.x, 0.f);
        tv.y = fmaxf(pd.y - ps.y + bb4.y, 0.f);
        tv.z = fmaxf(pd.z - ps.z + bb4.z, 0.f);
        tv.w = fmaxf(pd.w - ps.w + bb4.w, 0.f);
        *(float4*)&st[wave][kh][o * 4] = tv;
    };
    auto layer2_out = [&](int g) {
        float acc0 = 0.f, acc1 = 0.f;
        #pragma unroll
        for (int i = 0; i < 64; i += 4) {
            const float4 t0 = *(const float4*)&st[wave][0][kh * 64 + i];
            const float4 t1 = *(const float4*)&st[wave][1][kh * 64 + i];
            acc0 = fmaf(t0.x, w2r[i + 0], acc0);
            acc0 = fmaf(t0.y, w2r[i + 1], acc0);
            acc0 = fmaf(t0.z, w2r[i + 2], acc0);
            acc0 = fmaf(t0.w, w2r[i + 3], acc0);
            acc1 = fmaf(t1.x, w2r[i + 0], acc1);
            acc1 = fmaf(t1.y, w2r[i + 1], acc1);
            acc1 = fmaf(t1.z, w2r[i + 2], acc1);
            acc1 = fmaf(t1.w, w2r[i + 3], acc1);
        }
        float a0 = acc0 + __shfl_xor(acc0, 32);
        float u0 = fmaxf(a0 + b2r, 0.f) * w3r;
        #pragma unroll
        for (int m = 16; m; m >>= 1) u0 += __shfl_xor(u0, m);
        float a1 = acc1 + __shfl_xor(acc1, 32);
        float u1 = fmaxf(a1 + b2r, 0.f) * w3r;
        #pragma unroll
        for (int m = 16; m; m >>= 1) u1 += __shfl_xor(u1, m);
        if (lane == 0) {
            out[e0 + g * 2 + 0] = u0 + b3r;
            out[e0 + g * 2 + 1] = u1 + b3r;
        }
    };

    // prologue: load pass-0 rows
    {
        const int e = e0 + kh;
        const int src = eli[e];
        const int dst = eli[N_LABEL + e];
        pd = *(const float4*)&p[(size_t)dst * 128 + o * 4];
        ps = *(const float4*)&p[(size_t)src * 128 + o * 4];
    }

    #pragma unroll 2
    for (int g = 0; g < 7; ++g) {
        stage();
        // prefetch pass g+1 rows; independent of layer2 -> stays in flight
        const int en = e0 + (g + 1) * 2 + kh;
        const int nsrc = eli[en];
        const int ndst = eli[N_LABEL + en];
        float4 npd = *(const float4*)&p[(size_t)ndst * 128 + o * 4];
        float4 nps = *(const float4*)&p[(size_t)nsrc * 128 + o * 4];
        layer2_out(g);
        pd = npd;
        ps = nps;
    }
    // epilogue pass (g = 7), no prefetch
    stage();
    layer2_out(7);
}

// ---------------- launch ----------------
extern "C" void kernel_launch(void* const* d_in, const int* in_sizes, int n_in,
                              void* d_out, int out_size, void* d_ws, size_t ws_size,
                              hipStream_t stream) {
    const float* x   = (const float*)d_in[0];
    const int*   ei  = (const int*)d_in[1];
    const int*   eli = (const int*)d_in[2];
    const float* Wg  = (const float*)d_in[3];
    // d_in[4] = b_gcn : cancels in h[dst]-h[src], unused
    const float* W1  = (const float*)d_in[5];
    const float* b1  = (const float*)d_in[6];
    const float* W2  = (const float*)d_in[7];
    const float* b2  = (const float*)d_in[8];
    const float* W3  = (const float*)d_in[9];
    const float* b3  = (const float*)d_in[10];
    float* out = (float*)d_out;

    // ---- workspace layout (bytes), all regions disjoint & 16B-aligned ----
    char* ws = (char*)d_ws;
    float*  dis    = (float*)(ws + 0);           // 400 KB
    int*    cnt    = (int*)(ws + 524288);        // 400 KB
    int*    cursor = (int*)(ws + 1048576);       // 400 KB
    int*    rowptr = (int*)(ws + 1572864);       // 400 KB + 4
    int*    bsum   = (int*)(ws + 2000000);       // 512 B (98 ints)
    int*    csr    = (int*)(ws + 2097152);       // 3.2 MB (4 MB reserved)
    float*  Wf     = (float*)(ws + 6291456);     // 128 KB
    ushort* Bh     = (ushort*)(ws + 6422528);    // 64 KB
    ushort* Bl     = (ushort*)(ws + 6488064);    // 64 KB
    float*  qs     = (float*)(ws + 8388608);     // 51.2 MB
    float*  p      = (float*)(ws + 59588608);    // 51.2 MB

    const int NB = (N_NODES + 1023) / 1024;      // 98

    // CSR build + degree norm
    k_zero2<<<(N_NODES + 255) / 256, 256, 0, stream>>>(cnt, cursor);
    k_count<<<(N_EDGES + 255) / 256, 256, 0, stream>>>(ei, cnt);
    k_dis<<<(N_NODES + 255) / 256, 256, 0, stream>>>(cnt, dis);
    k_bsum<<<NB, 1024, 0, stream>>>(cnt, bsum);
    k_bscan<<<1, 128, 0, stream>>>(bsum, NB);
    k_rowptr<<<NB, 1024, 0, stream>>>(cnt, bsum, rowptr);
    k_fill<<<(N_EDGES + 255) / 256, 256, 0, stream>>>(ei, rowptr, cursor, csr);

    // Wf = W_gcn @ W1   [256,256]@[256,128]  (tiny, stays fp32)
    gemm_f32<<<dim3(2, 1), 256, 0, stream>>>(Wg, W1, Wf, 256, 128, 256, nullptr);

    // Wf -> bf16 hi/lo fragment-linear
    k_wsplit<<<128, 256, 0, stream>>>(Wf, Bh, Bl);

    // qs = (x @ Wf) * dis[row]  via split-bf16 MFMA
    gemm_mfma<<<(N_NODES + 127) / 128, 256, 0, stream>>>(x, Bh, Bl, dis, qs);

    // p[i] = dis[i] * (qs[i] + sum_{src->i} qs[src])
    k_gather<<<(N_NODES + 3) / 4, 256, 0, stream>>>(qs, rowptr, csr, dis, p);

    // fused per-edge MLP: 16 edges/wave, 4 waves/block
    k_edge_mlp<<<N_LABEL / 64, 256, 0, stream>>>(p, eli, b1, W2, b2, W3, b3, out);
}